// Round 1
// baseline (215.958 us; speedup 1.0000x reference)
//
#include <hip/hip_runtime.h>
#include <stdint.h>
#include <stddef.h>

#define IN_F   1024
#define OUT_F  1024
#define NROWS  16384
#define NTERMS 10
#define BK     64
#define KT     (IN_F / BK)   // 16 K-tiles

typedef __bf16 bf16x8 __attribute__((ext_vector_type(8)));
typedef float  f32x4  __attribute__((ext_vector_type(4)));
typedef unsigned short u16x8 __attribute__((ext_vector_type(8)));

union V8 { u16x8 u; bf16x8 b; };

__device__ __forceinline__ unsigned short f2bf(float f) {
    unsigned int u = __float_as_uint(f);
    unsigned int r = (u + 0x7FFFu + ((u >> 16) & 1u)) >> 16;
    return (unsigned short)r;
}

// ---------------------------------------------------------------- cast x -> bf16
__global__ void cast_x_kernel(const float* __restrict__ x, unsigned short* __restrict__ xb) {
    size_t i = ((size_t)blockIdx.x * 256 + threadIdx.x) * 8;
    float4 a = *(const float4*)(x + i);
    float4 b = *(const float4*)(x + i + 4);
    u16x8 o;
    o[0] = f2bf(a.x); o[1] = f2bf(a.y); o[2] = f2bf(a.z); o[3] = f2bf(a.w);
    o[4] = f2bf(b.x); o[5] = f2bf(b.y); o[6] = f2bf(b.z); o[7] = f2bf(b.w);
    *(u16x8*)(xb + i) = o;
}

// ------------------------------------------- base W -> bf16 ; mean spline W -> bf16
__global__ __launch_bounds__(256)
void prep_w_kernel(const float* __restrict__ bw, const float* __restrict__ sw,
                   unsigned short* __restrict__ wb, unsigned short* __restrict__ wm) {
    __shared__ float s[256 * NTERMS];
    const int tid = threadIdx.x;
    const size_t base = (size_t)blockIdx.x * 256;
    const float4* src = (const float4*)(sw + base * NTERMS);
#pragma unroll
    for (int it = 0; it < 3; ++it) {
        int j = tid + it * 256;
        if (j < (256 * NTERMS) / 4) ((float4*)s)[j] = src[j];
    }
    __syncthreads();
    float sum = 0.f;
#pragma unroll
    for (int t = 0; t < NTERMS; ++t) sum += s[tid * NTERMS + t];
    size_t i = base + tid;
    wm[i] = f2bf(sum * 0.1f);
    wb[i] = f2bf(bw[i]);
}

// ---------------------------------------------------------------- fused dual GEMM
// out[m][n] = silu( sum_k x[m][k]*Wb[n][k] ) + sum_k x[m][k]*Wm[n][k]
//
// 8-phase-style schedule (T3+T4+T5 per catalog), dual-B 256x128 tile:
//   512 threads = 8 waves (4M x 2N); per wave 64 rows x 64 cols x {base,spline}.
//   BK=64, double-buffered LDS: 2 buf x 4 units (A-half0, A-half1, Wb, Wm),
//   each unit 128x64 bf16 = 16 KiB -> 128 KiB total.
//   Per K-tile 4 phases: (s0,k0) (s1,k0) (s0,k1) (s1,k1); A-frags reused across s.
//   One 16 KiB unit prefetched per phase (2 x global_load_lds x 512 thr), issue
//   order A0,A1,Wb,Wm for tile t+1 during tile t. Counted vmcnt: boundary wait
//   vmcnt(2) (A0,A1,Wb of next tile done; Wm may stay in flight), Wm-visibility
//   wait vmcnt(2) at end of phase 0. Never vmcnt(0) in steady state.
//   XOR chunk swizzle (c ^ (r&7)) on all tiles: stage pre-swizzled global source,
//   linear LDS dest (global_load_lds constraint), swizzled ds_read.
#define GLL16(GP, LP) __builtin_amdgcn_global_load_lds( \
    (const __attribute__((address_space(1))) unsigned int*)(GP), \
    (__attribute__((address_space(3))) unsigned int*)(LP), 16, 0, 0)

__global__ __launch_bounds__(512, 2)
void kan_gemm(const unsigned short* __restrict__ xb,
              const unsigned short* __restrict__ wbq,
              const unsigned short* __restrict__ wmq,
              float* __restrict__ out)
{
    // [dbuf][unit: A0, A1, Wb, Wm][128 rows x 64 cols]
    __shared__ __align__(16) unsigned short lds[2][4][128 * 64];

    const int tid  = threadIdx.x;
    const int lane = tid & 63;
    const int wave = tid >> 6;
    const int wm_  = wave >> 1;      // 0..3 : M quarter (64 rows)
    const int wn_  = wave & 1;       // 0..1 : N half (64 cols)
    const int rowl = lane & 15;
    const int quad = lane >> 4;
    const int ah   = wm_ >> 1;       // which A unit this wave reads

    const int m0 = blockIdx.x * 256;
    const int n0 = blockIdx.y * 128;

    // ---- staging addressing: thread covers chunks e0=tid, e1=tid+512 of a unit
    // chunk e: row r=e>>3, slot cd=e&7; global chunk gc = cd ^ (r&7).
    // (tid+512)>>3 = r0+64 and (r0+64)&7 == r0&7, so both loads share c0.
    const int r0 = tid >> 3;
    const int c0 = (tid & 7) ^ (r0 & 7);
    const unsigned short* gA  = xb  + (size_t)(m0 + r0) * IN_F + c0 * 8;
    const unsigned short* gBb = wbq + (size_t)(n0 + r0) * IN_F + c0 * 8;
    const unsigned short* gBm = wmq + (size_t)(n0 + r0) * IN_F + c0 * 8;
    const int ldst0 = tid * 8;
    const int ldst1 = (tid + 512) * 8;

    // ---- fragment read offsets (elems within a 128x64 unit), swizzle-matched
    int aoff[4][2], boff[4][2];
#pragma unroll
    for (int mt = 0; mt < 4; ++mt) {
        int lr = (wm_ & 1) * 64 + mt * 16 + rowl;
#pragma unroll
        for (int ks = 0; ks < 2; ++ks)
            aoff[mt][ks] = lr * 64 + (((ks * 4 + quad) ^ (lr & 7)) * 8);
    }
#pragma unroll
    for (int nt = 0; nt < 4; ++nt) {
        int br = wn_ * 64 + nt * 16 + rowl;
#pragma unroll
        for (int ks = 0; ks < 2; ++ks)
            boff[nt][ks] = br * 64 + (((ks * 4 + quad) ^ (br & 7)) * 8);
    }

    f32x4 acc[2][4][4];
#pragma unroll
    for (int s = 0; s < 2; ++s)
#pragma unroll
        for (int mt = 0; mt < 4; ++mt)
#pragma unroll
            for (int nt = 0; nt < 4; ++nt)
                acc[s][mt][nt] = (f32x4){0.f, 0.f, 0.f, 0.f};

    // ---- prologue: stage tile 0 into buf 0 (issue order A0, A1, Wb, Wm)
    GLL16(gA,               &lds[0][0][ldst0]);
    GLL16(gA + 64 * IN_F,   &lds[0][0][ldst1]);
    GLL16(gA + 128 * IN_F,  &lds[0][1][ldst0]);
    GLL16(gA + 192 * IN_F,  &lds[0][1][ldst1]);
    GLL16(gBb,              &lds[0][2][ldst0]);
    GLL16(gBb + 64 * IN_F,  &lds[0][2][ldst1]);
    GLL16(gBm,              &lds[0][3][ldst0]);
    GLL16(gBm + 64 * IN_F,  &lds[0][3][ldst1]);
    asm volatile("s_waitcnt vmcnt(2)" ::: "memory");   // A0,A1,Wb done; Wm may fly
    __builtin_amdgcn_s_barrier();
    __builtin_amdgcn_sched_barrier(0);

#pragma unroll 2
    for (int t = 0; t < KT; ++t) {
        const int cur = t & 1;
        const int nxt = cur ^ 1;
        const bool more = (t + 1) < KT;
        const int kn = (t + 1) * BK;
        const unsigned short* uA  = &lds[cur][ah][0];
        const unsigned short* uBb = &lds[cur][2][0];
        const unsigned short* uBm = &lds[cur][3][0];

        V8 a[4], b[4];

        // ================= phase 0: s=0, ksub=0 =================
#pragma unroll
        for (int mt = 0; mt < 4; ++mt) a[mt].u = *(const u16x8*)(uA + aoff[mt][0]);
#pragma unroll
        for (int nt = 0; nt < 4; ++nt) b[nt].u = *(const u16x8*)(uBb + boff[nt][0]);
        if (more) {
            GLL16(gA + kn,              &lds[nxt][0][ldst0]);
            GLL16(gA + kn + 64 * IN_F,  &lds[nxt][0][ldst1]);
        }
        __builtin_amdgcn_s_barrier();
        asm volatile("s_waitcnt lgkmcnt(0)" ::: "memory");
        __builtin_amdgcn_sched_barrier(0);
        __builtin_amdgcn_s_setprio(1);
#pragma unroll
        for (int mt = 0; mt < 4; ++mt)
#pragma unroll
            for (int nt = 0; nt < 4; ++nt)
                acc[0][mt][nt] = __builtin_amdgcn_mfma_f32_16x16x32_bf16(
                    a[mt].b, b[nt].b, acc[0][mt][nt], 0, 0, 0);
        __builtin_amdgcn_s_setprio(0);
        // ensure this tile's Wm unit is visible before phase 1 reads it
        if (more) asm volatile("s_waitcnt vmcnt(2)" ::: "memory");
        else      asm volatile("s_waitcnt vmcnt(0)" ::: "memory");
        __builtin_amdgcn_s_barrier();
        __builtin_amdgcn_sched_barrier(0);

        // ================= phase 1: s=1, ksub=0 (A frags reused) =================
#pragma unroll
        for (int nt = 0; nt < 4; ++nt) b[nt].u = *(const u16x8*)(uBm + boff[nt][0]);
        if (more) {
            GLL16(gA + kn + 128 * IN_F, &lds[nxt][1][ldst0]);
            GLL16(gA + kn + 192 * IN_F, &lds[nxt][1][ldst1]);
        }
        __builtin_amdgcn_s_barrier();
        asm volatile("s_waitcnt lgkmcnt(0)" ::: "memory");
        __builtin_amdgcn_sched_barrier(0);
        __builtin_amdgcn_s_setprio(1);
#pragma unroll
        for (int mt = 0; mt < 4; ++mt)
#pragma unroll
            for (int nt = 0; nt < 4; ++nt)
                acc[1][mt][nt] = __builtin_amdgcn_mfma_f32_16x16x32_bf16(
                    a[mt].b, b[nt].b, acc[1][mt][nt], 0, 0, 0);
        __builtin_amdgcn_s_setprio(0);
        __builtin_amdgcn_s_barrier();

        // ================= phase 2: s=0, ksub=1 =================
#pragma unroll
        for (int mt = 0; mt < 4; ++mt) a[mt].u = *(const u16x8*)(uA + aoff[mt][1]);
#pragma unroll
        for (int nt = 0; nt < 4; ++nt) b[nt].u = *(const u16x8*)(uBb + boff[nt][1]);
        if (more) {
            GLL16(gBb + kn,             &lds[nxt][2][ldst0]);
            GLL16(gBb + kn + 64 * IN_F, &lds[nxt][2][ldst1]);
        }
        __builtin_amdgcn_s_barrier();
        asm volatile("s_waitcnt lgkmcnt(0)" ::: "memory");
        __builtin_amdgcn_sched_barrier(0);
        __builtin_amdgcn_s_setprio(1);
#pragma unroll
        for (int mt = 0; mt < 4; ++mt)
#pragma unroll
            for (int nt = 0; nt < 4; ++nt)
                acc[0][mt][nt] = __builtin_amdgcn_mfma_f32_16x16x32_bf16(
                    a[mt].b, b[nt].b, acc[0][mt][nt], 0, 0, 0);
        __builtin_amdgcn_s_setprio(0);
        __builtin_amdgcn_s_barrier();

        // ================= phase 3: s=1, ksub=1 (A frags reused) =================
#pragma unroll
        for (int nt = 0; nt < 4; ++nt) b[nt].u = *(const u16x8*)(uBm + boff[nt][1]);
        if (more) {
            GLL16(gBm + kn,             &lds[nxt][3][ldst0]);
            GLL16(gBm + kn + 64 * IN_F, &lds[nxt][3][ldst1]);
        }
        __builtin_amdgcn_s_barrier();
        asm volatile("s_waitcnt lgkmcnt(0)" ::: "memory");
        __builtin_amdgcn_sched_barrier(0);
        __builtin_amdgcn_s_setprio(1);
#pragma unroll
        for (int mt = 0; mt < 4; ++mt)
#pragma unroll
            for (int nt = 0; nt < 4; ++nt)
                acc[1][mt][nt] = __builtin_amdgcn_mfma_f32_16x16x32_bf16(
                    a[mt].b, b[nt].b, acc[1][mt][nt], 0, 0, 0);
        __builtin_amdgcn_s_setprio(0);
        // tile boundary: next tile's A0,A1,Wb done; its Wm may stay in flight
        asm volatile("s_waitcnt vmcnt(2)" ::: "memory");
        __builtin_amdgcn_s_barrier();
        __builtin_amdgcn_sched_barrier(0);
    }

    // ---- epilogue: silu(base) + spline, fp32 store
    // C/D layout (16x16x32): col = lane&15, row = quad*4 + reg
#pragma unroll
    for (int mt = 0; mt < 4; ++mt)
#pragma unroll
        for (int nt = 0; nt < 4; ++nt)
#pragma unroll
            for (int r = 0; r < 4; ++r) {
                float vb = acc[0][mt][nt][r];
                float vm = acc[1][mt][nt][r];
                float o  = vb / (1.0f + __expf(-vb)) + vm;
                int row = m0 + wm_ * 64 + mt * 16 + quad * 4 + r;
                int col = n0 + wn_ * 64 + nt * 16 + rowl;
                out[(size_t)row * OUT_F + col] = o;
            }
}

extern "C" void kernel_launch(void* const* d_in, const int* in_sizes, int n_in,
                              void* d_out, int out_size, void* d_ws, size_t ws_size,
                              hipStream_t stream) {
    const float* x  = (const float*)d_in[0];   // [16384,1024]
    const float* bw = (const float*)d_in[1];   // [1024,1024]
    const float* sw = (const float*)d_in[2];   // [1024,1024,10]
    float* out = (float*)d_out;                // [16384,1024]

    unsigned short* xb  = (unsigned short*)d_ws;
    unsigned short* wbq = xb + (size_t)NROWS * IN_F;
    unsigned short* wmq = wbq + (size_t)OUT_F * IN_F;

    cast_x_kernel<<<dim3((NROWS * IN_F) / (256 * 8)), dim3(256), 0, stream>>>(x, xb);
    prep_w_kernel<<<dim3((OUT_F * IN_F) / 256), dim3(256), 0, stream>>>(bw, sw, wbq, wmq);
    kan_gemm<<<dim3(NROWS / 256, OUT_F / 128), dim3(512), 0, stream>>>(xb, wbq, wmq, out);
}